// Round 7
// baseline (393.519 us; speedup 1.0000x reference)
//
#include <hip/hip_runtime.h>
#include <math.h>

#define THREADS 256
#define TMASK ((1u << 19) - 1u)

// scale_l = 8 * 256^(l/15) - 1 ; res_l = ceil(scale_l)+1 (dense only for l<4)
static __device__ __constant__ float kScale[16] = {
    7.0f,          10.57815398f,  15.75670563f,  23.25146503f,
    34.09839735f,  49.79683366f,  72.51669472f,  105.39843246f,
    152.98718950f, 221.86092960f, 321.53978800f, 465.80191600f,
    674.58804640f, 976.75780270f, 1414.07882380f, 2047.0f};
static __device__ __constant__ int kRes[4] = {8, 12, 17, 25};

// ---------------------------------------------------------------------------
// K1: hashed levels 4..15. One thread = one (point, level). Blocks are
// swizzled so each XCD (blockIdx & 7, observed round-robin mapping) works on
// 1-2 hash tables -> 4MB table stays L2-resident per XCD.
//   phase 1 (r < CH):  XCD x -> level 4+x
//   phase 2 (r >= CH): XCD pair (x>>1) -> level 12+(x>>1), chunks split by x&1
// feat layout: [12][N] float2 (both store and re-load coalesced).
// ---------------------------------------------------------------------------
__global__ void __launch_bounds__(THREADS, 6)
htrf_encode(const float* __restrict__ xyzs, const float* __restrict__ grid,
            float2* __restrict__ feat, int N, int CH, int H0) {
  const int b = blockIdx.x;
  const int x = b & 7;
  const int r = b >> 3;
  int level, chunk;
  if (r < CH) {
    level = 4 + x;
    chunk = r;
  } else {
    const int j = r - CH;  // [0, H0)
    level = 12 + (x >> 1);
    chunk = (x & 1) ? (H0 + j) : j;
    if (chunk >= CH) return;
  }
  const int n = chunk * THREADS + threadIdx.x;
  if (n >= N) return;

  const float4 p = reinterpret_cast<const float4*>(xyzs)[n];
  const float q0 = (p.x + 1.0f) * 0.5f;
  const float q1 = (p.y + 1.0f) * 0.5f;
  const float q2 = (p.z + 1.0f) * 0.5f;
  const float q3 = p.w;

  const float s = kScale[level];
  const float pos0 = fmaf(q0, s, 0.5f);
  const float pos1 = fmaf(q1, s, 0.5f);
  const float pos2 = fmaf(q2, s, 0.5f);
  const float pos3 = fmaf(q3, s, 0.5f);
  const float fl0 = floorf(pos0), fl1 = floorf(pos1);
  const float fl2 = floorf(pos2), fl3 = floorf(pos3);
  const float f0 = pos0 - fl0, f1 = pos1 - fl1;
  const float f2 = pos2 - fl2, f3 = pos3 - fl3;
  const int g0 = (int)fl0, g1 = (int)fl1, g2 = (int)fl2, g3 = (int)fl3;

  float wxy[4], wzt[4];
  {
    const float u0 = 1.0f - f0, u1 = 1.0f - f1, u2 = 1.0f - f2, u3 = 1.0f - f3;
    wxy[0] = u0 * u1; wxy[1] = f0 * u1; wxy[2] = u0 * f1; wxy[3] = f0 * f1;
    wzt[0] = u2 * u3; wzt[1] = f2 * u3; wzt[2] = u2 * f3; wzt[3] = f2 * f3;
  }

  // levels >= 4 are always hashed (res^4 > T)
  const unsigned hx0 = (unsigned)g0,               hx1 = (unsigned)(g0 + 1);
  const unsigned hy0 = (unsigned)g1 * 2654435761u, hy1 = (unsigned)(g1 + 1) * 2654435761u;
  const unsigned hz0 = (unsigned)g2 * 805459861u,  hz1 = (unsigned)(g2 + 1) * 805459861u;
  const unsigned ht0 = (unsigned)g3 * 3674351687u, ht1 = (unsigned)(g3 + 1) * 3674351687u;
  const unsigned sxy[4] = {hx0 ^ hy0, hx1 ^ hy0, hx0 ^ hy1, hx1 ^ hy1};
  const unsigned szt[4] = {hz0 ^ ht0, hz1 ^ ht0, hz0 ^ ht1, hz1 ^ ht1};

  const float2* __restrict__ gl =
      reinterpret_cast<const float2*>(grid) + ((size_t)level << 19);
  float2 vv[16];
  #pragma unroll
  for (int cc = 0; cc < 16; ++cc) {
    const unsigned idx = (sxy[cc & 3] ^ szt[cc >> 2]) & TMASK;
    vv[cc] = gl[idx];  // 16 independent loads in flight
  }
  float a0 = 0.0f, a1 = 0.0f;
  #pragma unroll
  for (int cc = 0; cc < 16; ++cc) {
    const float w = wxy[cc & 3] * wzt[cc >> 2];
    a0 = fmaf(w, vv[cc].x, a0);
    a1 = fmaf(w, vv[cc].y, a1);
  }
  feat[(size_t)(level - 4) * N + n] = make_float2(a0, a1);
}

// ---------------------------------------------------------------------------
// K2: dense levels 0..3 inline (tables <= 3.1MB, cache-resident) + MLPs.
// ---------------------------------------------------------------------------
__global__ void __launch_bounds__(THREADS)
htrf_mlp(const float* __restrict__ xyzs, const float* __restrict__ dirs,
         const float* __restrict__ grid, const float* __restrict__ W1,
         const float* __restrict__ W2, const float* __restrict__ Wc1,
         const float* __restrict__ Wc2, const float* __restrict__ Wc3,
         const float2* __restrict__ feat, float* __restrict__ out, int N) {
  const int n = blockIdx.x * THREADS + threadIdx.x;
  if (n >= N) return;

  const float4 p = reinterpret_cast<const float4*>(xyzs)[n];
  const float q0 = (p.x + 1.0f) * 0.5f;
  const float q1 = (p.y + 1.0f) * 0.5f;
  const float q2 = (p.z + 1.0f) * 0.5f;
  const float q3 = p.w;

  float fr[32];
  // dense levels 0..3 (fully unrolled -> static fr indices)
  #pragma unroll
  for (int l = 0; l < 4; ++l) {
    const float s = kScale[l];
    const float pos0 = fmaf(q0, s, 0.5f);
    const float pos1 = fmaf(q1, s, 0.5f);
    const float pos2 = fmaf(q2, s, 0.5f);
    const float pos3 = fmaf(q3, s, 0.5f);
    const float fl0 = floorf(pos0), fl1 = floorf(pos1);
    const float fl2 = floorf(pos2), fl3 = floorf(pos3);
    const float f0 = pos0 - fl0, f1 = pos1 - fl1;
    const float f2 = pos2 - fl2, f3 = pos3 - fl3;
    const int g0 = (int)fl0, g1 = (int)fl1, g2 = (int)fl2, g3 = (int)fl3;

    float wxy[4], wzt[4];
    {
      const float u0 = 1.0f - f0, u1 = 1.0f - f1, u2 = 1.0f - f2, u3 = 1.0f - f3;
      wxy[0] = u0 * u1; wxy[1] = f0 * u1; wxy[2] = u0 * f1; wxy[3] = f0 * f1;
      wzt[0] = u2 * u3; wzt[1] = f2 * u3; wzt[2] = u2 * f3; wzt[3] = f2 * f3;
    }
    const int rr = kRes[l];
    const int r2 = rr * rr, r3 = r2 * rr;
    const int ix0 = g0, ix1 = g0 + 1;
    const int iy0 = g1 * rr, iy1 = (g1 + 1) * rr;
    const int iz0 = g2 * r2, iz1 = (g2 + 1) * r2;
    const int it0 = g3 * r3, it1 = (g3 + 1) * r3;
    const int sxy[4] = {ix0 + iy0, ix1 + iy0, ix0 + iy1, ix1 + iy1};
    const int szt[4] = {iz0 + it0, iz1 + it0, iz0 + it1, iz1 + it1};
    const float2* __restrict__ gl =
        reinterpret_cast<const float2*>(grid) + ((size_t)l << 19);
    float2 vv[16];
    #pragma unroll
    for (int cc = 0; cc < 16; ++cc) {
      const int v = sxy[cc & 3] + szt[cc >> 2];
      const int idx = v < (int)TMASK ? v : (int)TMASK;
      vv[cc] = gl[idx];
    }
    float a0 = 0.0f, a1 = 0.0f;
    #pragma unroll
    for (int cc = 0; cc < 16; ++cc) {
      const float w = wxy[cc & 3] * wzt[cc >> 2];
      a0 = fmaf(w, vv[cc].x, a0);
      a1 = fmaf(w, vv[cc].y, a1);
    }
    fr[2 * l] = a0;
    fr[2 * l + 1] = a1;
  }
  // hashed levels 4..15 from workspace (coalesced: consecutive n)
  #pragma unroll
  for (int l = 0; l < 12; ++l) {
    const float2 v = feat[(size_t)l * N + n];
    fr[8 + 2 * l] = v.x;
    fr[9 + 2 * l] = v.y;
  }

  // ---------------- MLP1: 32 -> 64(relu) -> 16, fused accumulate ----------------
  float h[16];
  #pragma unroll
  for (int i = 0; i < 16; ++i) h[i] = 0.0f;

  #pragma unroll 1
  for (int j = 0; j < 64; ++j) {  // j uniform -> weight rows via scalar loads
    const float* __restrict__ w = W1 + j * 32;
    float b0 = 0.f, b1 = 0.f, b2 = 0.f, b3 = 0.f;
    #pragma unroll
    for (int k = 0; k < 32; k += 4) {
      b0 = fmaf(fr[k + 0], w[k + 0], b0);
      b1 = fmaf(fr[k + 1], w[k + 1], b1);
      b2 = fmaf(fr[k + 2], w[k + 2], b2);
      b3 = fmaf(fr[k + 3], w[k + 3], b3);
    }
    const float act = fmaxf((b0 + b1) + (b2 + b3), 0.0f);
    #pragma unroll
    for (int i = 0; i < 16; ++i) h[i] = fmaf(act, W2[i * 64 + j], h[i]);
  }
  const float sigma = expf(h[0]);

  // ---------------- SH degree-4 + concat ----------------
  const float dxr = dirs[3 * n + 0], dyr = dirs[3 * n + 1], dzr = dirs[3 * n + 2];
  const float x = fmaf(dxr, 2.0f, -1.0f);
  const float y = fmaf(dyr, 2.0f, -1.0f);
  const float z = fmaf(dzr, 2.0f, -1.0f);
  const float xy = x * y, xz = x * z, yz = y * z;
  const float x2 = x * x, y2 = y * y, z2 = z * z;
  float ci[32];
  ci[0]  = 0.28209479177387814f;
  ci[1]  = -0.48860251190291987f * y;
  ci[2]  = 0.48860251190291987f * z;
  ci[3]  = -0.48860251190291987f * x;
  ci[4]  = 1.0925484305920792f * xy;
  ci[5]  = -1.0925484305920792f * yz;
  ci[6]  = 0.94617469575756f * z2 - 0.31539156525252f;
  ci[7]  = -1.0925484305920792f * xz;
  ci[8]  = 0.5462742152960396f * x2 - 0.5462742152960396f * y2;
  ci[9]  = 0.5900435899266435f * y * (-3.0f * x2 + y2);
  ci[10] = 2.890611442640554f * xy * z;
  ci[11] = 0.4570457994644657f * y * (1.0f - 5.0f * z2);
  ci[12] = 0.3731763325901154f * z * (5.0f * z2 - 3.0f);
  ci[13] = 0.4570457994644657f * x * (1.0f - 5.0f * z2);
  ci[14] = 1.445305721320277f * z * (x2 - y2);
  ci[15] = 0.5900435899266435f * x * (-x2 + 3.0f * y2);
  #pragma unroll
  for (int i = 0; i < 16; ++i) ci[16 + i] = h[i];

  // ---------------- color MLP: 32 -> 64(relu) -> 64(relu) -> 3(sigmoid) --------
  float c2p[64];
  #pragma unroll
  for (int i = 0; i < 64; ++i) c2p[i] = 0.0f;

  #pragma unroll 1
  for (int j = 0; j < 64; ++j) {
    const float* __restrict__ w = Wc1 + j * 32;
    float b0 = 0.f, b1 = 0.f, b2 = 0.f, b3 = 0.f;
    #pragma unroll
    for (int k = 0; k < 32; k += 4) {
      b0 = fmaf(ci[k + 0], w[k + 0], b0);
      b1 = fmaf(ci[k + 1], w[k + 1], b1);
      b2 = fmaf(ci[k + 2], w[k + 2], b2);
      b3 = fmaf(ci[k + 3], w[k + 3], b3);
    }
    const float act = fmaxf((b0 + b1) + (b2 + b3), 0.0f);
    #pragma unroll
    for (int i = 0; i < 64; ++i) c2p[i] = fmaf(act, Wc2[i * 64 + j], c2p[i]);
  }

  float l0a = 0.f, l0b = 0.f, l1a = 0.f, l1b = 0.f, l2a = 0.f, l2b = 0.f;
  #pragma unroll
  for (int i = 0; i < 64; i += 2) {
    const float a0r = fmaxf(c2p[i], 0.0f);
    const float a1r = fmaxf(c2p[i + 1], 0.0f);
    l0a = fmaf(a0r, Wc3[0 * 64 + i], l0a);
    l0b = fmaf(a1r, Wc3[0 * 64 + i + 1], l0b);
    l1a = fmaf(a0r, Wc3[1 * 64 + i], l1a);
    l1b = fmaf(a1r, Wc3[1 * 64 + i + 1], l1b);
    l2a = fmaf(a0r, Wc3[2 * 64 + i], l2a);
    l2b = fmaf(a1r, Wc3[2 * 64 + i + 1], l2b);
  }
  const float col0 = 1.0f / (1.0f + expf(-(l0a + l0b)));
  const float col1 = 1.0f / (1.0f + expf(-(l1a + l1b)));
  const float col2 = 1.0f / (1.0f + expf(-(l2a + l2b)));

  out[3 * n + 0] = col0;
  out[3 * n + 1] = col1;
  out[3 * n + 2] = col2;
  out[3 * N + n] = sigma;
}

// ---------------------------------------------------------------------------
// Fallback: round-2 fused kernel (used only if ws_size is too small).
// ---------------------------------------------------------------------------
__global__ void __launch_bounds__(THREADS)
htrf_fused(const float* __restrict__ xyzs, const float* __restrict__ dirs,
           const float* __restrict__ grid, const float* __restrict__ W1,
           const float* __restrict__ W2, const float* __restrict__ Wc1,
           const float* __restrict__ Wc2, const float* __restrict__ Wc3,
           float* __restrict__ out, int N) {
  __shared__ float sbuf[THREADS * 33];
  const int tid = threadIdx.x;
  const int n = blockIdx.x * THREADS + tid;
  if (n >= N) return;
  float* __restrict__ my = sbuf + tid * 33;

  const float4 p = reinterpret_cast<const float4*>(xyzs)[n];
  const float q0 = (p.x + 1.0f) * 0.5f;
  const float q1 = (p.y + 1.0f) * 0.5f;
  const float q2 = (p.z + 1.0f) * 0.5f;
  const float q3 = p.w;

  #pragma unroll 1
  for (int l = 0; l < 16; ++l) {
    const float s = kScale[l];
    const float pos0 = fmaf(q0, s, 0.5f);
    const float pos1 = fmaf(q1, s, 0.5f);
    const float pos2 = fmaf(q2, s, 0.5f);
    const float pos3 = fmaf(q3, s, 0.5f);
    const float fl0 = floorf(pos0), fl1 = floorf(pos1);
    const float fl2 = floorf(pos2), fl3 = floorf(pos3);
    const float f0 = pos0 - fl0, f1 = pos1 - fl1;
    const float f2 = pos2 - fl2, f3 = pos3 - fl3;
    const int g0 = (int)fl0, g1 = (int)fl1, g2 = (int)fl2, g3 = (int)fl3;

    float wxy[4], wzt[4];
    {
      const float u0 = 1.0f - f0, u1 = 1.0f - f1, u2 = 1.0f - f2, u3 = 1.0f - f3;
      wxy[0] = u0 * u1; wxy[1] = f0 * u1; wxy[2] = u0 * f1; wxy[3] = f0 * f1;
      wzt[0] = u2 * u3; wzt[1] = f2 * u3; wzt[2] = u2 * f3; wzt[3] = f2 * f3;
    }

    unsigned idx[16];
    if (l < 4) {
      const int rr = kRes[l];
      const int r2 = rr * rr, r3 = r2 * rr;
      const int ix0 = g0, ix1 = g0 + 1;
      const int iy0 = g1 * rr, iy1 = (g1 + 1) * rr;
      const int iz0 = g2 * r2, iz1 = (g2 + 1) * r2;
      const int it0 = g3 * r3, it1 = (g3 + 1) * r3;
      const int sxy[4] = {ix0 + iy0, ix1 + iy0, ix0 + iy1, ix1 + iy1};
      const int szt[4] = {iz0 + it0, iz1 + it0, iz0 + it1, iz1 + it1};
      #pragma unroll
      for (int cc = 0; cc < 16; ++cc) {
        const int v = sxy[cc & 3] + szt[cc >> 2];
        idx[cc] = (unsigned)(v < (int)TMASK ? v : (int)TMASK);
      }
    } else {
      const unsigned hx0 = (unsigned)g0,               hx1 = (unsigned)(g0 + 1);
      const unsigned hy0 = (unsigned)g1 * 2654435761u, hy1 = (unsigned)(g1 + 1) * 2654435761u;
      const unsigned hz0 = (unsigned)g2 * 805459861u,  hz1 = (unsigned)(g2 + 1) * 805459861u;
      const unsigned ht0 = (unsigned)g3 * 3674351687u, ht1 = (unsigned)(g3 + 1) * 3674351687u;
      const unsigned sxy[4] = {hx0 ^ hy0, hx1 ^ hy0, hx0 ^ hy1, hx1 ^ hy1};
      const unsigned szt[4] = {hz0 ^ ht0, hz1 ^ ht0, hz0 ^ ht1, hz1 ^ ht1};
      #pragma unroll
      for (int cc = 0; cc < 16; ++cc)
        idx[cc] = (sxy[cc & 3] ^ szt[cc >> 2]) & TMASK;
    }

    const float2* __restrict__ gl =
        reinterpret_cast<const float2*>(grid) + ((size_t)l << 19);
    float2 vv[16];
    #pragma unroll
    for (int cc = 0; cc < 16; ++cc) vv[cc] = gl[idx[cc]];
    float a0 = 0.0f, a1 = 0.0f;
    #pragma unroll
    for (int cc = 0; cc < 16; ++cc) {
      const float w = wxy[cc & 3] * wzt[cc >> 2];
      a0 = fmaf(w, vv[cc].x, a0);
      a1 = fmaf(w, vv[cc].y, a1);
    }
    my[2 * l] = a0;
    my[2 * l + 1] = a1;
  }

  float fr[32];
  #pragma unroll
  for (int k = 0; k < 32; ++k) fr[k] = my[k];

  float h[16];
  #pragma unroll
  for (int i = 0; i < 16; ++i) h[i] = 0.0f;

  #pragma unroll 1
  for (int j = 0; j < 64; ++j) {
    const float* __restrict__ w = W1 + j * 32;
    float b0 = 0.f, b1 = 0.f, b2 = 0.f, b3 = 0.f;
    #pragma unroll
    for (int k = 0; k < 32; k += 4) {
      b0 = fmaf(fr[k + 0], w[k + 0], b0);
      b1 = fmaf(fr[k + 1], w[k + 1], b1);
      b2 = fmaf(fr[k + 2], w[k + 2], b2);
      b3 = fmaf(fr[k + 3], w[k + 3], b3);
    }
    const float act = fmaxf((b0 + b1) + (b2 + b3), 0.0f);
    #pragma unroll
    for (int i = 0; i < 16; ++i) h[i] = fmaf(act, W2[i * 64 + j], h[i]);
  }
  const float sigma = expf(h[0]);

  const float dxr = dirs[3 * n + 0], dyr = dirs[3 * n + 1], dzr = dirs[3 * n + 2];
  const float x = fmaf(dxr, 2.0f, -1.0f);
  const float y = fmaf(dyr, 2.0f, -1.0f);
  const float z = fmaf(dzr, 2.0f, -1.0f);
  const float xy = x * y, xz = x * z, yz = y * z;
  const float x2 = x * x, y2 = y * y, z2 = z * z;
  float ci[32];
  ci[0]  = 0.28209479177387814f;
  ci[1]  = -0.48860251190291987f * y;
  ci[2]  = 0.48860251190291987f * z;
  ci[3]  = -0.48860251190291987f * x;
  ci[4]  = 1.0925484305920792f * xy;
  ci[5]  = -1.0925484305920792f * yz;
  ci[6]  = 0.94617469575756f * z2 - 0.31539156525252f;
  ci[7]  = -1.0925484305920792f * xz;
  ci[8]  = 0.5462742152960396f * x2 - 0.5462742152960396f * y2;
  ci[9]  = 0.5900435899266435f * y * (-3.0f * x2 + y2);
  ci[10] = 2.890611442640554f * xy * z;
  ci[11] = 0.4570457994644657f * y * (1.0f - 5.0f * z2);
  ci[12] = 0.3731763325901154f * z * (5.0f * z2 - 3.0f);
  ci[13] = 0.4570457994644657f * x * (1.0f - 5.0f * z2);
  ci[14] = 1.445305721320277f * z * (x2 - y2);
  ci[15] = 0.5900435899266435f * x * (-x2 + 3.0f * y2);
  #pragma unroll
  for (int i = 0; i < 16; ++i) ci[16 + i] = h[i];

  float c2p[64];
  #pragma unroll
  for (int i = 0; i < 64; ++i) c2p[i] = 0.0f;

  #pragma unroll 1
  for (int j = 0; j < 64; ++j) {
    const float* __restrict__ w = Wc1 + j * 32;
    float b0 = 0.f, b1 = 0.f, b2 = 0.f, b3 = 0.f;
    #pragma unroll
    for (int k = 0; k < 32; k += 4) {
      b0 = fmaf(ci[k + 0], w[k + 0], b0);
      b1 = fmaf(ci[k + 1], w[k + 1], b1);
      b2 = fmaf(ci[k + 2], w[k + 2], b2);
      b3 = fmaf(ci[k + 3], w[k + 3], b3);
    }
    const float act = fmaxf((b0 + b1) + (b2 + b3), 0.0f);
    #pragma unroll
    for (int i = 0; i < 64; ++i) c2p[i] = fmaf(act, Wc2[i * 64 + j], c2p[i]);
  }

  float l0a = 0.f, l0b = 0.f, l1a = 0.f, l1b = 0.f, l2a = 0.f, l2b = 0.f;
  #pragma unroll
  for (int i = 0; i < 64; i += 2) {
    const float a0r = fmaxf(c2p[i], 0.0f);
    const float a1r = fmaxf(c2p[i + 1], 0.0f);
    l0a = fmaf(a0r, Wc3[0 * 64 + i], l0a);
    l0b = fmaf(a1r, Wc3[0 * 64 + i + 1], l0b);
    l1a = fmaf(a0r, Wc3[1 * 64 + i], l1a);
    l1b = fmaf(a1r, Wc3[1 * 64 + i + 1], l1b);
    l2a = fmaf(a0r, Wc3[2 * 64 + i], l2a);
    l2b = fmaf(a1r, Wc3[2 * 64 + i + 1], l2b);
  }
  const float col0 = 1.0f / (1.0f + expf(-(l0a + l0b)));
  const float col1 = 1.0f / (1.0f + expf(-(l1a + l1b)));
  const float col2 = 1.0f / (1.0f + expf(-(l2a + l2b)));

  out[3 * n + 0] = col0;
  out[3 * n + 1] = col1;
  out[3 * n + 2] = col2;
  out[3 * N + n] = sigma;
}

extern "C" void kernel_launch(void* const* d_in, const int* in_sizes, int n_in,
                              void* d_out, int out_size, void* d_ws, size_t ws_size,
                              hipStream_t stream) {
  const int N = in_sizes[0] / 4;
  const size_t need = (size_t)12 * (size_t)N * sizeof(float2);
  if (ws_size >= need) {
    const int CH = (N + THREADS - 1) / THREADS;   // point chunks per level
    const int H0 = (CH + 1) / 2;                  // phase-2 split point
    const int NB = 8 * (CH + H0);                 // phase1: 8*CH, phase2: 8*H0
    htrf_encode<<<dim3(NB), dim3(THREADS), 0, stream>>>(
        (const float*)d_in[0], (const float*)d_in[2], (float2*)d_ws, N, CH, H0);
    htrf_mlp<<<dim3((N + THREADS - 1) / THREADS), dim3(THREADS), 0, stream>>>(
        (const float*)d_in[0], (const float*)d_in[1], (const float*)d_in[2],
        (const float*)d_in[3], (const float*)d_in[4], (const float*)d_in[5],
        (const float*)d_in[6], (const float*)d_in[7], (const float2*)d_ws,
        (float*)d_out, N);
  } else {
    htrf_fused<<<dim3((N + THREADS - 1) / THREADS), dim3(THREADS), 0, stream>>>(
        (const float*)d_in[0], (const float*)d_in[1], (const float*)d_in[2],
        (const float*)d_in[3], (const float*)d_in[4], (const float*)d_in[5],
        (const float*)d_in[6], (const float*)d_in[7], (float*)d_out, N);
  }
}

// Round 8
// 370.779 us; speedup vs baseline: 1.0613x; 1.0613x over previous
//
#include <hip/hip_runtime.h>
#include <math.h>

#define THREADS 256
#define TMASK ((1u << 19) - 1u)

// scale_l = 8 * 256^(l/15) - 1 ; res_l = ceil(scale_l)+1 (dense only for l<4)
static __device__ __constant__ float kScale[16] = {
    7.0f,          10.57815398f,  15.75670563f,  23.25146503f,
    34.09839735f,  49.79683366f,  72.51669472f,  105.39843246f,
    152.98718950f, 221.86092960f, 321.53978800f, 465.80191600f,
    674.58804640f, 976.75780270f, 1414.07882380f, 2047.0f};
static __device__ __constant__ int kRes[4] = {8, 12, 17, 25};

// ---------------------------------------------------------------------------
// K1: hashed levels 4..15, corner-cooperative. Wave of 64 = 4 points x 16
// corners per iteration (16 iterations -> 64 points/wave, 256/block).
// Corner pairs (c, c^1) differ only in hash bit0 when g0 is even -> same 64B
// line -> coalescer merges -> ~12 lines/point instead of 16 (the L2 request
// rate is the measured limiter: 280G lines/s ~= 91% of channel ceiling).
// XCD affinity: blockIdx&7 -> level (phase 1), XCD pairs on levels 12-15.
// ---------------------------------------------------------------------------
__global__ void __launch_bounds__(THREADS, 6)
htrf_encode(const float* __restrict__ xyzs, const float* __restrict__ grid,
            float2* __restrict__ feat, int N, int CH, int H0) {
  const int b = blockIdx.x;
  const int x = b & 7;
  const int r = b >> 3;
  int level, chunk;
  if (r < CH) {
    level = 4 + x;
    chunk = r;
  } else {
    const int j = r - CH;  // [0, H0)
    level = 12 + (x >> 1);
    chunk = (x & 1) ? (H0 + j) : j;
    if (chunk >= CH) return;
  }
  const int tid = threadIdx.x;
  const int wave = tid >> 6;
  const int lane = tid & 63;
  const int p_local = lane >> 4;   // 0..3: which point of this iteration
  const int c = lane & 15;         // corner id
  const int cx = c & 1, cy = (c >> 1) & 1, cz = (c >> 2) & 1, ct = (c >> 3) & 1;

  const int base = chunk * THREADS + wave * 64;  // 64 points per wave
  // preload: lane i holds point (base+i)
  const int gp = base + lane;
  float4 pre = make_float4(0.f, 0.f, 0.f, 0.f);
  if (gp < N) pre = reinterpret_cast<const float4*>(xyzs)[gp];

  const float s = kScale[level];
  const float2* __restrict__ gl =
      reinterpret_cast<const float2*>(grid) + ((size_t)level << 19);

  #pragma unroll 4
  for (int it = 0; it < 16; ++it) {
    const int src = it * 4 + p_local;  // lane holding this point's data
    const float q0 = (__shfl(pre.x, src, 64) + 1.0f) * 0.5f;
    const float q1 = (__shfl(pre.y, src, 64) + 1.0f) * 0.5f;
    const float q2 = (__shfl(pre.z, src, 64) + 1.0f) * 0.5f;
    const float q3 = __shfl(pre.w, src, 64);

    const float pos0 = fmaf(q0, s, 0.5f);
    const float pos1 = fmaf(q1, s, 0.5f);
    const float pos2 = fmaf(q2, s, 0.5f);
    const float pos3 = fmaf(q3, s, 0.5f);
    const float fl0 = floorf(pos0), fl1 = floorf(pos1);
    const float fl2 = floorf(pos2), fl3 = floorf(pos3);
    const float f0 = pos0 - fl0, f1 = pos1 - fl1;
    const float f2 = pos2 - fl2, f3 = pos3 - fl3;
    const int g0 = (int)fl0, g1 = (int)fl1, g2 = (int)fl2, g3 = (int)fl3;

    // per-lane corner hash (levels >= 4 always hashed)
    const unsigned ux = (unsigned)(g0 + cx);
    const unsigned uy = (unsigned)(g1 + cy) * 2654435761u;
    const unsigned uz = (unsigned)(g2 + cz) * 805459861u;
    const unsigned ut = (unsigned)(g3 + ct) * 3674351687u;
    const unsigned idx = (ux ^ uy ^ uz ^ ut) & TMASK;

    const float w = (cx ? f0 : 1.0f - f0) * (cy ? f1 : 1.0f - f1) *
                    (cz ? f2 : 1.0f - f2) * (ct ? f3 : 1.0f - f3);

    const float2 v = gl[idx];  // 1 instr: 4 points x 16 corners, x-pairs merge
    float s0 = w * v.x;
    float s1 = w * v.y;
    // butterfly reduce over the 16-lane corner group
    s0 += __shfl_xor(s0, 1, 64);  s1 += __shfl_xor(s1, 1, 64);
    s0 += __shfl_xor(s0, 2, 64);  s1 += __shfl_xor(s1, 2, 64);
    s0 += __shfl_xor(s0, 4, 64);  s1 += __shfl_xor(s1, 4, 64);
    s0 += __shfl_xor(s0, 8, 64);  s1 += __shfl_xor(s1, 8, 64);

    const int n = base + it * 4 + p_local;
    if (c == 0 && n < N) feat[(size_t)(level - 4) * N + n] = make_float2(s0, s1);
  }
}

// ---------------------------------------------------------------------------
// K2: dense levels 0..3 + MLP1 (32->64relu->16). Writes sigma to out and
// h[16] into ws, ALIASING the feat region (rows are read fully into fr[]
// before any write; each thread touches only column n -> race-free).
// Low VGPR (~85) -> high occupancy to hide the dense-table gathers.
// ---------------------------------------------------------------------------
__global__ void __launch_bounds__(THREADS, 4)
htrf_mlp1(const float* __restrict__ xyzs, const float* __restrict__ grid,
          const float* __restrict__ W1, const float* __restrict__ W2,
          float* __restrict__ ws, float* __restrict__ out, int N) {
  const int n = blockIdx.x * THREADS + threadIdx.x;
  if (n >= N) return;

  const float4 p = reinterpret_cast<const float4*>(xyzs)[n];
  const float q0 = (p.x + 1.0f) * 0.5f;
  const float q1 = (p.y + 1.0f) * 0.5f;
  const float q2 = (p.z + 1.0f) * 0.5f;
  const float q3 = p.w;

  float fr[32];
  // dense levels 0..3 (fully unrolled -> static fr indices)
  #pragma unroll
  for (int l = 0; l < 4; ++l) {
    const float s = kScale[l];
    const float pos0 = fmaf(q0, s, 0.5f);
    const float pos1 = fmaf(q1, s, 0.5f);
    const float pos2 = fmaf(q2, s, 0.5f);
    const float pos3 = fmaf(q3, s, 0.5f);
    const float fl0 = floorf(pos0), fl1 = floorf(pos1);
    const float fl2 = floorf(pos2), fl3 = floorf(pos3);
    const float f0 = pos0 - fl0, f1 = pos1 - fl1;
    const float f2 = pos2 - fl2, f3 = pos3 - fl3;
    const int g0 = (int)fl0, g1 = (int)fl1, g2 = (int)fl2, g3 = (int)fl3;

    float wxy[4], wzt[4];
    {
      const float u0 = 1.0f - f0, u1 = 1.0f - f1, u2 = 1.0f - f2, u3 = 1.0f - f3;
      wxy[0] = u0 * u1; wxy[1] = f0 * u1; wxy[2] = u0 * f1; wxy[3] = f0 * f1;
      wzt[0] = u2 * u3; wzt[1] = f2 * u3; wzt[2] = u2 * f3; wzt[3] = f2 * f3;
    }
    const int rr = kRes[l];
    const int r2 = rr * rr, r3 = r2 * rr;
    const int sxy[4] = {g0 + g1 * rr, g0 + 1 + g1 * rr,
                        g0 + (g1 + 1) * rr, g0 + 1 + (g1 + 1) * rr};
    const int szt[4] = {g2 * r2 + g3 * r3, (g2 + 1) * r2 + g3 * r3,
                        g2 * r2 + (g3 + 1) * r3, (g2 + 1) * r2 + (g3 + 1) * r3};
    const float2* __restrict__ gl =
        reinterpret_cast<const float2*>(grid) + ((size_t)l << 19);
    float2 vv[16];
    #pragma unroll
    for (int cc = 0; cc < 16; ++cc) {
      const int v = sxy[cc & 3] + szt[cc >> 2];
      const int idx = v < (int)TMASK ? v : (int)TMASK;
      vv[cc] = gl[idx];
    }
    float a0 = 0.0f, a1 = 0.0f;
    #pragma unroll
    for (int cc = 0; cc < 16; ++cc) {
      const float w = wxy[cc & 3] * wzt[cc >> 2];
      a0 = fmaf(w, vv[cc].x, a0);
      a1 = fmaf(w, vv[cc].y, a1);
    }
    fr[2 * l] = a0;
    fr[2 * l + 1] = a1;
  }
  // hashed levels 4..15 from workspace (coalesced)
  const float2* __restrict__ feat = reinterpret_cast<const float2*>(ws);
  #pragma unroll
  for (int l = 0; l < 12; ++l) {
    const float2 v = feat[(size_t)l * N + n];
    fr[8 + 2 * l] = v.x;
    fr[9 + 2 * l] = v.y;
  }

  float h[16];
  #pragma unroll
  for (int i = 0; i < 16; ++i) h[i] = 0.0f;

  #pragma unroll 1
  for (int j = 0; j < 64; ++j) {  // j uniform -> weight rows via scalar loads
    const float* __restrict__ w = W1 + j * 32;
    float b0 = 0.f, b1 = 0.f, b2 = 0.f, b3 = 0.f;
    #pragma unroll
    for (int k = 0; k < 32; k += 4) {
      b0 = fmaf(fr[k + 0], w[k + 0], b0);
      b1 = fmaf(fr[k + 1], w[k + 1], b1);
      b2 = fmaf(fr[k + 2], w[k + 2], b2);
      b3 = fmaf(fr[k + 3], w[k + 3], b3);
    }
    const float act = fmaxf((b0 + b1) + (b2 + b3), 0.0f);
    #pragma unroll
    for (int i = 0; i < 16; ++i) h[i] = fmaf(act, W2[i * 64 + j], h[i]);
  }
  out[3 * N + n] = expf(h[0]);  // sigma
  // stash h (aliases consumed feat rows; column-exclusive per thread)
  #pragma unroll
  for (int i = 0; i < 16; ++i) ws[(size_t)i * N + n] = h[i];
}

// ---------------------------------------------------------------------------
// K3: SH + color MLP (32->64relu->64relu->3 sigmoid).
// ---------------------------------------------------------------------------
__global__ void __launch_bounds__(THREADS, 3)
htrf_color(const float* __restrict__ dirs, const float* __restrict__ Wc1,
           const float* __restrict__ Wc2, const float* __restrict__ Wc3,
           const float* __restrict__ ws, float* __restrict__ out, int N) {
  const int n = blockIdx.x * THREADS + threadIdx.x;
  if (n >= N) return;

  const float dxr = dirs[3 * n + 0], dyr = dirs[3 * n + 1], dzr = dirs[3 * n + 2];
  const float x = fmaf(dxr, 2.0f, -1.0f);
  const float y = fmaf(dyr, 2.0f, -1.0f);
  const float z = fmaf(dzr, 2.0f, -1.0f);
  const float xy = x * y, xz = x * z, yz = y * z;
  const float x2 = x * x, y2 = y * y, z2 = z * z;
  float ci[32];
  ci[0]  = 0.28209479177387814f;
  ci[1]  = -0.48860251190291987f * y;
  ci[2]  = 0.48860251190291987f * z;
  ci[3]  = -0.48860251190291987f * x;
  ci[4]  = 1.0925484305920792f * xy;
  ci[5]  = -1.0925484305920792f * yz;
  ci[6]  = 0.94617469575756f * z2 - 0.31539156525252f;
  ci[7]  = -1.0925484305920792f * xz;
  ci[8]  = 0.5462742152960396f * x2 - 0.5462742152960396f * y2;
  ci[9]  = 0.5900435899266435f * y * (-3.0f * x2 + y2);
  ci[10] = 2.890611442640554f * xy * z;
  ci[11] = 0.4570457994644657f * y * (1.0f - 5.0f * z2);
  ci[12] = 0.3731763325901154f * z * (5.0f * z2 - 3.0f);
  ci[13] = 0.4570457994644657f * x * (1.0f - 5.0f * z2);
  ci[14] = 1.445305721320277f * z * (x2 - y2);
  ci[15] = 0.5900435899266435f * x * (-x2 + 3.0f * y2);
  #pragma unroll
  for (int i = 0; i < 16; ++i) ci[16 + i] = ws[(size_t)i * N + n];

  float c2p[64];
  #pragma unroll
  for (int i = 0; i < 64; ++i) c2p[i] = 0.0f;

  #pragma unroll 1
  for (int j = 0; j < 64; ++j) {
    const float* __restrict__ w = Wc1 + j * 32;
    float b0 = 0.f, b1 = 0.f, b2 = 0.f, b3 = 0.f;
    #pragma unroll
    for (int k = 0; k < 32; k += 4) {
      b0 = fmaf(ci[k + 0], w[k + 0], b0);
      b1 = fmaf(ci[k + 1], w[k + 1], b1);
      b2 = fmaf(ci[k + 2], w[k + 2], b2);
      b3 = fmaf(ci[k + 3], w[k + 3], b3);
    }
    const float act = fmaxf((b0 + b1) + (b2 + b3), 0.0f);
    #pragma unroll
    for (int i = 0; i < 64; ++i) c2p[i] = fmaf(act, Wc2[i * 64 + j], c2p[i]);
  }

  float l0a = 0.f, l0b = 0.f, l1a = 0.f, l1b = 0.f, l2a = 0.f, l2b = 0.f;
  #pragma unroll
  for (int i = 0; i < 64; i += 2) {
    const float a0r = fmaxf(c2p[i], 0.0f);
    const float a1r = fmaxf(c2p[i + 1], 0.0f);
    l0a = fmaf(a0r, Wc3[0 * 64 + i], l0a);
    l0b = fmaf(a1r, Wc3[0 * 64 + i + 1], l0b);
    l1a = fmaf(a0r, Wc3[1 * 64 + i], l1a);
    l1b = fmaf(a1r, Wc3[1 * 64 + i + 1], l1b);
    l2a = fmaf(a0r, Wc3[2 * 64 + i], l2a);
    l2b = fmaf(a1r, Wc3[2 * 64 + i + 1], l2b);
  }
  out[3 * n + 0] = 1.0f / (1.0f + expf(-(l0a + l0b)));
  out[3 * n + 1] = 1.0f / (1.0f + expf(-(l1a + l1b)));
  out[3 * n + 2] = 1.0f / (1.0f + expf(-(l2a + l2b)));
}

// ---------------------------------------------------------------------------
// Fallback: round-2 fused kernel (used only if ws_size is too small).
// ---------------------------------------------------------------------------
__global__ void __launch_bounds__(THREADS)
htrf_fused(const float* __restrict__ xyzs, const float* __restrict__ dirs,
           const float* __restrict__ grid, const float* __restrict__ W1,
           const float* __restrict__ W2, const float* __restrict__ Wc1,
           const float* __restrict__ Wc2, const float* __restrict__ Wc3,
           float* __restrict__ out, int N) {
  __shared__ float sbuf[THREADS * 33];
  const int tid = threadIdx.x;
  const int n = blockIdx.x * THREADS + tid;
  if (n >= N) return;
  float* __restrict__ my = sbuf + tid * 33;

  const float4 p = reinterpret_cast<const float4*>(xyzs)[n];
  const float q0 = (p.x + 1.0f) * 0.5f;
  const float q1 = (p.y + 1.0f) * 0.5f;
  const float q2 = (p.z + 1.0f) * 0.5f;
  const float q3 = p.w;

  #pragma unroll 1
  for (int l = 0; l < 16; ++l) {
    const float s = kScale[l];
    const float pos0 = fmaf(q0, s, 0.5f);
    const float pos1 = fmaf(q1, s, 0.5f);
    const float pos2 = fmaf(q2, s, 0.5f);
    const float pos3 = fmaf(q3, s, 0.5f);
    const float fl0 = floorf(pos0), fl1 = floorf(pos1);
    const float fl2 = floorf(pos2), fl3 = floorf(pos3);
    const float f0 = pos0 - fl0, f1 = pos1 - fl1;
    const float f2 = pos2 - fl2, f3 = pos3 - fl3;
    const int g0 = (int)fl0, g1 = (int)fl1, g2 = (int)fl2, g3 = (int)fl3;

    float wxy[4], wzt[4];
    {
      const float u0 = 1.0f - f0, u1 = 1.0f - f1, u2 = 1.0f - f2, u3 = 1.0f - f3;
      wxy[0] = u0 * u1; wxy[1] = f0 * u1; wxy[2] = u0 * f1; wxy[3] = f0 * f1;
      wzt[0] = u2 * u3; wzt[1] = f2 * u3; wzt[2] = u2 * f3; wzt[3] = f2 * f3;
    }

    unsigned idx[16];
    if (l < 4) {
      const int rr = kRes[l];
      const int r2 = rr * rr, r3 = r2 * rr;
      const int sxy[4] = {g0 + g1 * rr, g0 + 1 + g1 * rr,
                          g0 + (g1 + 1) * rr, g0 + 1 + (g1 + 1) * rr};
      const int szt[4] = {g2 * r2 + g3 * r3, (g2 + 1) * r2 + g3 * r3,
                          g2 * r2 + (g3 + 1) * r3, (g2 + 1) * r2 + (g3 + 1) * r3};
      #pragma unroll
      for (int cc = 0; cc < 16; ++cc) {
        const int v = sxy[cc & 3] + szt[cc >> 2];
        idx[cc] = (unsigned)(v < (int)TMASK ? v : (int)TMASK);
      }
    } else {
      const unsigned hx0 = (unsigned)g0,               hx1 = (unsigned)(g0 + 1);
      const unsigned hy0 = (unsigned)g1 * 2654435761u, hy1 = (unsigned)(g1 + 1) * 2654435761u;
      const unsigned hz0 = (unsigned)g2 * 805459861u,  hz1 = (unsigned)(g2 + 1) * 805459861u;
      const unsigned ht0 = (unsigned)g3 * 3674351687u, ht1 = (unsigned)(g3 + 1) * 3674351687u;
      const unsigned sxy[4] = {hx0 ^ hy0, hx1 ^ hy0, hx0 ^ hy1, hx1 ^ hy1};
      const unsigned szt[4] = {hz0 ^ ht0, hz1 ^ ht0, hz0 ^ ht1, hz1 ^ ht1};
      #pragma unroll
      for (int cc = 0; cc < 16; ++cc)
        idx[cc] = (sxy[cc & 3] ^ szt[cc >> 2]) & TMASK;
    }

    const float2* __restrict__ gl =
        reinterpret_cast<const float2*>(grid) + ((size_t)l << 19);
    float2 vv[16];
    #pragma unroll
    for (int cc = 0; cc < 16; ++cc) vv[cc] = gl[idx[cc]];
    float a0 = 0.0f, a1 = 0.0f;
    #pragma unroll
    for (int cc = 0; cc < 16; ++cc) {
      const float w = wxy[cc & 3] * wzt[cc >> 2];
      a0 = fmaf(w, vv[cc].x, a0);
      a1 = fmaf(w, vv[cc].y, a1);
    }
    my[2 * l] = a0;
    my[2 * l + 1] = a1;
  }

  float fr[32];
  #pragma unroll
  for (int k = 0; k < 32; ++k) fr[k] = my[k];

  float h[16];
  #pragma unroll
  for (int i = 0; i < 16; ++i) h[i] = 0.0f;

  #pragma unroll 1
  for (int j = 0; j < 64; ++j) {
    const float* __restrict__ w = W1 + j * 32;
    float b0 = 0.f, b1 = 0.f, b2 = 0.f, b3 = 0.f;
    #pragma unroll
    for (int k = 0; k < 32; k += 4) {
      b0 = fmaf(fr[k + 0], w[k + 0], b0);
      b1 = fmaf(fr[k + 1], w[k + 1], b1);
      b2 = fmaf(fr[k + 2], w[k + 2], b2);
      b3 = fmaf(fr[k + 3], w[k + 3], b3);
    }
    const float act = fmaxf((b0 + b1) + (b2 + b3), 0.0f);
    #pragma unroll
    for (int i = 0; i < 16; ++i) h[i] = fmaf(act, W2[i * 64 + j], h[i]);
  }
  const float sigma = expf(h[0]);

  const float dxr = dirs[3 * n + 0], dyr = dirs[3 * n + 1], dzr = dirs[3 * n + 2];
  const float x = fmaf(dxr, 2.0f, -1.0f);
  const float y = fmaf(dyr, 2.0f, -1.0f);
  const float z = fmaf(dzr, 2.0f, -1.0f);
  const float xy = x * y, xz = x * z, yz = y * z;
  const float x2 = x * x, y2 = y * y, z2 = z * z;
  float ci[32];
  ci[0]  = 0.28209479177387814f;
  ci[1]  = -0.48860251190291987f * y;
  ci[2]  = 0.48860251190291987f * z;
  ci[3]  = -0.48860251190291987f * x;
  ci[4]  = 1.0925484305920792f * xy;
  ci[5]  = -1.0925484305920792f * yz;
  ci[6]  = 0.94617469575756f * z2 - 0.31539156525252f;
  ci[7]  = -1.0925484305920792f * xz;
  ci[8]  = 0.5462742152960396f * x2 - 0.5462742152960396f * y2;
  ci[9]  = 0.5900435899266435f * y * (-3.0f * x2 + y2);
  ci[10] = 2.890611442640554f * xy * z;
  ci[11] = 0.4570457994644657f * y * (1.0f - 5.0f * z2);
  ci[12] = 0.3731763325901154f * z * (5.0f * z2 - 3.0f);
  ci[13] = 0.4570457994644657f * x * (1.0f - 5.0f * z2);
  ci[14] = 1.445305721320277f * z * (x2 - y2);
  ci[15] = 0.5900435899266435f * x * (-x2 + 3.0f * y2);
  #pragma unroll
  for (int i = 0; i < 16; ++i) ci[16 + i] = h[i];

  float c2p[64];
  #pragma unroll
  for (int i = 0; i < 64; ++i) c2p[i] = 0.0f;

  #pragma unroll 1
  for (int j = 0; j < 64; ++j) {
    const float* __restrict__ w = Wc1 + j * 32;
    float b0 = 0.f, b1 = 0.f, b2 = 0.f, b3 = 0.f;
    #pragma unroll
    for (int k = 0; k < 32; k += 4) {
      b0 = fmaf(ci[k + 0], w[k + 0], b0);
      b1 = fmaf(ci[k + 1], w[k + 1], b1);
      b2 = fmaf(ci[k + 2], w[k + 2], b2);
      b3 = fmaf(ci[k + 3], w[k + 3], b3);
    }
    const float act = fmaxf((b0 + b1) + (b2 + b3), 0.0f);
    #pragma unroll
    for (int i = 0; i < 64; ++i) c2p[i] = fmaf(act, Wc2[i * 64 + j], c2p[i]);
  }

  float l0a = 0.f, l0b = 0.f, l1a = 0.f, l1b = 0.f, l2a = 0.f, l2b = 0.f;
  #pragma unroll
  for (int i = 0; i < 64; i += 2) {
    const float a0r = fmaxf(c2p[i], 0.0f);
    const float a1r = fmaxf(c2p[i + 1], 0.0f);
    l0a = fmaf(a0r, Wc3[0 * 64 + i], l0a);
    l0b = fmaf(a1r, Wc3[0 * 64 + i + 1], l0b);
    l1a = fmaf(a0r, Wc3[1 * 64 + i], l1a);
    l1b = fmaf(a1r, Wc3[1 * 64 + i + 1], l1b);
    l2a = fmaf(a0r, Wc3[2 * 64 + i], l2a);
    l2b = fmaf(a1r, Wc3[2 * 64 + i + 1], l2b);
  }
  out[3 * n + 0] = 1.0f / (1.0f + expf(-(l0a + l0b)));
  out[3 * n + 1] = 1.0f / (1.0f + expf(-(l1a + l1b)));
  out[3 * n + 2] = 1.0f / (1.0f + expf(-(l2a + l2b)));
  out[3 * N + n] = sigma;
}

extern "C" void kernel_launch(void* const* d_in, const int* in_sizes, int n_in,
                              void* d_out, int out_size, void* d_ws, size_t ws_size,
                              hipStream_t stream) {
  const int N = in_sizes[0] / 4;
  const size_t need = (size_t)12 * (size_t)N * sizeof(float2);  // 24MB; h aliases feat
  if (ws_size >= need) {
    const int CH = (N + THREADS - 1) / THREADS;   // point chunks per level
    const int H0 = (CH + 1) / 2;                  // phase-2 split point
    const int NB = 8 * (CH + H0);                 // phase1: 8*CH, phase2: 8*H0
    const int PB = (N + THREADS - 1) / THREADS;
    htrf_encode<<<dim3(NB), dim3(THREADS), 0, stream>>>(
        (const float*)d_in[0], (const float*)d_in[2], (float2*)d_ws, N, CH, H0);
    htrf_mlp1<<<dim3(PB), dim3(THREADS), 0, stream>>>(
        (const float*)d_in[0], (const float*)d_in[2], (const float*)d_in[3],
        (const float*)d_in[4], (float*)d_ws, (float*)d_out, N);
    htrf_color<<<dim3(PB), dim3(THREADS), 0, stream>>>(
        (const float*)d_in[1], (const float*)d_in[5], (const float*)d_in[6],
        (const float*)d_in[7], (const float*)d_ws, (float*)d_out, N);
  } else {
    htrf_fused<<<dim3((N + THREADS - 1) / THREADS), dim3(THREADS), 0, stream>>>(
        (const float*)d_in[0], (const float*)d_in[1], (const float*)d_in[2],
        (const float*)d_in[3], (const float*)d_in[4], (const float*)d_in[5],
        (const float*)d_in[6], (const float*)d_in[7], (float*)d_out, N);
  }
}

// Round 9
// 354.109 us; speedup vs baseline: 1.1113x; 1.0471x over previous
//
#include <hip/hip_runtime.h>
#include <math.h>

#define THREADS 256
#define TMASK ((1u << 19) - 1u)

typedef __attribute__((ext_vector_type(8))) short short8;
typedef __attribute__((ext_vector_type(4))) float f32x4;

// scale_l = 8 * 256^(l/15) - 1 ; res_l = ceil(scale_l)+1 (dense only for l<4)
static __device__ __constant__ float kScale[16] = {
    7.0f,          10.57815398f,  15.75670563f,  23.25146503f,
    34.09839735f,  49.79683366f,  72.51669472f,  105.39843246f,
    152.98718950f, 221.86092960f, 321.53978800f, 465.80191600f,
    674.58804640f, 976.75780270f, 1414.07882380f, 2047.0f};
static __device__ __constant__ int kRes[4] = {8, 12, 17, 25};

static __device__ __forceinline__ unsigned short f2bf(float f) {
  unsigned u = __builtin_bit_cast(unsigned, f);
  unsigned r = u + 0x7FFFu + ((u >> 16) & 1u);
  return (unsigned short)(r >> 16);
}

// ---------------------------------------------------------------------------
// K1: hashed levels 4..15, corner-cooperative (wave = 4 points x 16 corners
// per iteration). After butterfly, results are redistributed so lane L holds
// point base+L -> one fully-coalesced float2 store per lane (fixes round-8's
// partial-sector writes: WRITE 50->25MB).
// XCD affinity: blockIdx&7 -> level (phase 1), XCD pairs on levels 12-15.
// ---------------------------------------------------------------------------
__global__ void __launch_bounds__(THREADS, 6)
htrf_encode(const float* __restrict__ xyzs, const float* __restrict__ grid,
            float2* __restrict__ feat, int N, int CH, int H0) {
  const int b = blockIdx.x;
  const int x = b & 7;
  const int r = b >> 3;
  int level, chunk;
  if (r < CH) {
    level = 4 + x;
    chunk = r;
  } else {
    const int j = r - CH;  // [0, H0)
    level = 12 + (x >> 1);
    chunk = (x & 1) ? (H0 + j) : j;
    if (chunk >= CH) return;
  }
  const int tid = threadIdx.x;
  const int wave = tid >> 6;
  const int lane = tid & 63;
  const int p_local = lane >> 4;   // 0..3: which point of this iteration
  const int c = lane & 15;         // corner id
  const int cx = c & 1, cy = (c >> 1) & 1, cz = (c >> 2) & 1, ct = (c >> 3) & 1;

  const int base = chunk * THREADS + wave * 64;  // 64 points per wave
  const int gp = base + lane;
  float4 pre = make_float4(0.f, 0.f, 0.f, 0.f);
  if (gp < N) pre = reinterpret_cast<const float4*>(xyzs)[gp];

  const float s = kScale[level];
  const float2* __restrict__ gl =
      reinterpret_cast<const float2*>(grid) + ((size_t)level << 19);

  float r0 = 0.0f, r1 = 0.0f;
  #pragma unroll 4
  for (int it = 0; it < 16; ++it) {
    const int src = it * 4 + p_local;  // lane holding this point's data
    const float q0 = (__shfl(pre.x, src, 64) + 1.0f) * 0.5f;
    const float q1 = (__shfl(pre.y, src, 64) + 1.0f) * 0.5f;
    const float q2 = (__shfl(pre.z, src, 64) + 1.0f) * 0.5f;
    const float q3 = __shfl(pre.w, src, 64);

    const float pos0 = fmaf(q0, s, 0.5f);
    const float pos1 = fmaf(q1, s, 0.5f);
    const float pos2 = fmaf(q2, s, 0.5f);
    const float pos3 = fmaf(q3, s, 0.5f);
    const float fl0 = floorf(pos0), fl1 = floorf(pos1);
    const float fl2 = floorf(pos2), fl3 = floorf(pos3);
    const float f0 = pos0 - fl0, f1 = pos1 - fl1;
    const float f2 = pos2 - fl2, f3 = pos3 - fl3;
    const int g0 = (int)fl0, g1 = (int)fl1, g2 = (int)fl2, g3 = (int)fl3;

    const unsigned ux = (unsigned)(g0 + cx);
    const unsigned uy = (unsigned)(g1 + cy) * 2654435761u;
    const unsigned uz = (unsigned)(g2 + cz) * 805459861u;
    const unsigned ut = (unsigned)(g3 + ct) * 3674351687u;
    const unsigned idx = (ux ^ uy ^ uz ^ ut) & TMASK;

    const float w = (cx ? f0 : 1.0f - f0) * (cy ? f1 : 1.0f - f1) *
                    (cz ? f2 : 1.0f - f2) * (ct ? f3 : 1.0f - f3);

    const float2 v = gl[idx];
    float s0 = w * v.x;
    float s1 = w * v.y;
    // butterfly over the 16-lane corner group: all 16 lanes end with the sum
    s0 += __shfl_xor(s0, 1, 64);  s1 += __shfl_xor(s1, 1, 64);
    s0 += __shfl_xor(s0, 2, 64);  s1 += __shfl_xor(s1, 2, 64);
    s0 += __shfl_xor(s0, 4, 64);  s1 += __shfl_xor(s1, 4, 64);
    s0 += __shfl_xor(s0, 8, 64);  s1 += __shfl_xor(s1, 8, 64);
    // redistribute: lane L keeps the sum when it == L>>2, from group L&3
    const float t0 = __shfl(s0, (lane & 3) << 4, 64);
    const float t1 = __shfl(s1, (lane & 3) << 4, 64);
    if ((lane >> 2) == it) { r0 = t0; r1 = t1; }
  }
  if (gp < N) feat[(size_t)(level - 4) * N + gp] = make_float2(r0, r1);
}

// ---------------------------------------------------------------------------
// K2: fully-fused MLP via bf16 MFMA (mfma_f32_16x16x32_bf16).
// Block = 256 threads = 4 independent waves. Prep phase: thread<->point 1:1
// (dense levels 0-3, feat loads, SH) -> bf16 -> LDS. MFMA phase: wave w does
// 4 tiles of 16 points: L1(4 mfma) -> W2(2) -> Lc1(4) -> Lc2(8); Wc3 via
// VALU + 16-lane butterfly. Weights live in VGPR fragments (no per-iter
// weight loads -- the measured stall source of the scalar version).
// Fragment layouts (guide-verified): A: row=l&15, k=8*(l>>4)+i;
// B: col=l&15, k=8*(l>>4)+i; D: col=l&15, row=4*(l>>4)+reg.
// ---------------------------------------------------------------------------
__global__ void __launch_bounds__(THREADS, 3)
htrf_mlp_mfma(const float* __restrict__ xyzs, const float* __restrict__ dirs,
              const float* __restrict__ grid, const float* __restrict__ W1,
              const float* __restrict__ W2, const float* __restrict__ Wc1,
              const float* __restrict__ Wc2, const float* __restrict__ Wc3,
              const float2* __restrict__ feat, float* __restrict__ out, int N) {
  // rows padded: X/CI 40 bf16 (80B, 16B-aligned, bank-spread); ACT 72 bf16
  __shared__ unsigned short Xs[256 * 40];
  __shared__ unsigned short CIs[256 * 40];
  __shared__ unsigned short ACTs[4][16 * 72];
  __shared__ float W3s[192];

  const int tid = threadIdx.x;
  const int lane = tid & 63;
  const int wv = tid >> 6;
  const int m = lane & 15;   // row-in-tile / neuron-in-tile
  const int ks = lane >> 4;  // k-slice
  const int n = blockIdx.x * THREADS + tid;

  // ---- weight fragments: 8 contiguous floats per lane -> bf16x8 ----
  short8 w1f[4], wc1f[4], w2f[2], wc2f[4][2];
  #pragma unroll
  for (int t = 0; t < 4; ++t) {
    const float4 a = *reinterpret_cast<const float4*>(W1 + (t * 16 + m) * 32 + ks * 8);
    const float4 bq = *reinterpret_cast<const float4*>(W1 + (t * 16 + m) * 32 + ks * 8 + 4);
    short8 sv;
    sv[0]=(short)f2bf(a.x); sv[1]=(short)f2bf(a.y); sv[2]=(short)f2bf(a.z); sv[3]=(short)f2bf(a.w);
    sv[4]=(short)f2bf(bq.x); sv[5]=(short)f2bf(bq.y); sv[6]=(short)f2bf(bq.z); sv[7]=(short)f2bf(bq.w);
    w1f[t] = sv;
  }
  #pragma unroll
  for (int t = 0; t < 4; ++t) {
    const float4 a = *reinterpret_cast<const float4*>(Wc1 + (t * 16 + m) * 32 + ks * 8);
    const float4 bq = *reinterpret_cast<const float4*>(Wc1 + (t * 16 + m) * 32 + ks * 8 + 4);
    short8 sv;
    sv[0]=(short)f2bf(a.x); sv[1]=(short)f2bf(a.y); sv[2]=(short)f2bf(a.z); sv[3]=(short)f2bf(a.w);
    sv[4]=(short)f2bf(bq.x); sv[5]=(short)f2bf(bq.y); sv[6]=(short)f2bf(bq.z); sv[7]=(short)f2bf(bq.w);
    wc1f[t] = sv;
  }
  #pragma unroll
  for (int kk = 0; kk < 2; ++kk) {
    const float4 a = *reinterpret_cast<const float4*>(W2 + m * 64 + kk * 32 + ks * 8);
    const float4 bq = *reinterpret_cast<const float4*>(W2 + m * 64 + kk * 32 + ks * 8 + 4);
    short8 sv;
    sv[0]=(short)f2bf(a.x); sv[1]=(short)f2bf(a.y); sv[2]=(short)f2bf(a.z); sv[3]=(short)f2bf(a.w);
    sv[4]=(short)f2bf(bq.x); sv[5]=(short)f2bf(bq.y); sv[6]=(short)f2bf(bq.z); sv[7]=(short)f2bf(bq.w);
    w2f[kk] = sv;
  }
  #pragma unroll
  for (int t = 0; t < 4; ++t)
    #pragma unroll
    for (int kk = 0; kk < 2; ++kk) {
      const float4 a = *reinterpret_cast<const float4*>(Wc2 + (t * 16 + m) * 64 + kk * 32 + ks * 8);
      const float4 bq = *reinterpret_cast<const float4*>(Wc2 + (t * 16 + m) * 64 + kk * 32 + ks * 8 + 4);
      short8 sv;
      sv[0]=(short)f2bf(a.x); sv[1]=(short)f2bf(a.y); sv[2]=(short)f2bf(a.z); sv[3]=(short)f2bf(a.w);
      sv[4]=(short)f2bf(bq.x); sv[5]=(short)f2bf(bq.y); sv[6]=(short)f2bf(bq.z); sv[7]=(short)f2bf(bq.w);
      wc2f[t][kk] = sv;
    }
  if (tid < 192) W3s[tid] = Wc3[tid];

  // ---- prep: this thread's point -> X (32 feats) and CI[0..15] (SH) ----
  if (n < N) {
    const float4 p = reinterpret_cast<const float4*>(xyzs)[n];
    const float q0 = (p.x + 1.0f) * 0.5f;
    const float q1 = (p.y + 1.0f) * 0.5f;
    const float q2 = (p.z + 1.0f) * 0.5f;
    const float q3 = p.w;

    float fr[32];
    #pragma unroll
    for (int l = 0; l < 4; ++l) {
      const float s = kScale[l];
      const float pos0 = fmaf(q0, s, 0.5f);
      const float pos1 = fmaf(q1, s, 0.5f);
      const float pos2 = fmaf(q2, s, 0.5f);
      const float pos3 = fmaf(q3, s, 0.5f);
      const float fl0 = floorf(pos0), fl1 = floorf(pos1);
      const float fl2 = floorf(pos2), fl3 = floorf(pos3);
      const float f0 = pos0 - fl0, f1 = pos1 - fl1;
      const float f2 = pos2 - fl2, f3 = pos3 - fl3;
      const int g0 = (int)fl0, g1 = (int)fl1, g2 = (int)fl2, g3 = (int)fl3;

      float wxy[4], wzt[4];
      {
        const float u0 = 1.0f - f0, u1 = 1.0f - f1, u2 = 1.0f - f2, u3 = 1.0f - f3;
        wxy[0] = u0 * u1; wxy[1] = f0 * u1; wxy[2] = u0 * f1; wxy[3] = f0 * f1;
        wzt[0] = u2 * u3; wzt[1] = f2 * u3; wzt[2] = u2 * f3; wzt[3] = f2 * f3;
      }
      const int rr = kRes[l];
      const int r2 = rr * rr, r3 = r2 * rr;
      const int sxy[4] = {g0 + g1 * rr, g0 + 1 + g1 * rr,
                          g0 + (g1 + 1) * rr, g0 + 1 + (g1 + 1) * rr};
      const int szt[4] = {g2 * r2 + g3 * r3, (g2 + 1) * r2 + g3 * r3,
                          g2 * r2 + (g3 + 1) * r3, (g2 + 1) * r2 + (g3 + 1) * r3};
      const float2* __restrict__ gld =
          reinterpret_cast<const float2*>(grid) + ((size_t)l << 19);
      float2 vv[16];
      #pragma unroll
      for (int cc = 0; cc < 16; ++cc) {
        const int v = sxy[cc & 3] + szt[cc >> 2];
        const int idx = v < (int)TMASK ? v : (int)TMASK;
        vv[cc] = gld[idx];
      }
      float a0 = 0.0f, a1 = 0.0f;
      #pragma unroll
      for (int cc = 0; cc < 16; ++cc) {
        const float w = wxy[cc & 3] * wzt[cc >> 2];
        a0 = fmaf(w, vv[cc].x, a0);
        a1 = fmaf(w, vv[cc].y, a1);
      }
      fr[2 * l] = a0;
      fr[2 * l + 1] = a1;
    }
    #pragma unroll
    for (int l = 0; l < 12; ++l) {
      const float2 v = feat[(size_t)l * N + n];
      fr[8 + 2 * l] = v.x;
      fr[9 + 2 * l] = v.y;
    }
    #pragma unroll
    for (int g = 0; g < 4; ++g) {
      short8 sv;
      #pragma unroll
      for (int i = 0; i < 8; ++i) sv[i] = (short)f2bf(fr[g * 8 + i]);
      *reinterpret_cast<short8*>(&Xs[tid * 40 + g * 8]) = sv;
    }

    // SH deg 4
    const float dxr = dirs[3 * n + 0], dyr = dirs[3 * n + 1], dzr = dirs[3 * n + 2];
    const float x = fmaf(dxr, 2.0f, -1.0f);
    const float y = fmaf(dyr, 2.0f, -1.0f);
    const float z = fmaf(dzr, 2.0f, -1.0f);
    const float xy = x * y, xz = x * z, yz = y * z;
    const float x2 = x * x, y2 = y * y, z2 = z * z;
    float sh[16];
    sh[0]  = 0.28209479177387814f;
    sh[1]  = -0.48860251190291987f * y;
    sh[2]  = 0.48860251190291987f * z;
    sh[3]  = -0.48860251190291987f * x;
    sh[4]  = 1.0925484305920792f * xy;
    sh[5]  = -1.0925484305920792f * yz;
    sh[6]  = 0.94617469575756f * z2 - 0.31539156525252f;
    sh[7]  = -1.0925484305920792f * xz;
    sh[8]  = 0.5462742152960396f * x2 - 0.5462742152960396f * y2;
    sh[9]  = 0.5900435899266435f * y * (-3.0f * x2 + y2);
    sh[10] = 2.890611442640554f * xy * z;
    sh[11] = 0.4570457994644657f * y * (1.0f - 5.0f * z2);
    sh[12] = 0.3731763325901154f * z * (5.0f * z2 - 3.0f);
    sh[13] = 0.4570457994644657f * x * (1.0f - 5.0f * z2);
    sh[14] = 1.445305721320277f * z * (x2 - y2);
    sh[15] = 0.5900435899266435f * x * (-x2 + 3.0f * y2);
    #pragma unroll
    for (int g = 0; g < 2; ++g) {
      short8 sv;
      #pragma unroll
      for (int i = 0; i < 8; ++i) sv[i] = (short)f2bf(sh[g * 8 + i]);
      *reinterpret_cast<short8*>(&CIs[tid * 40 + g * 8]) = sv;
    }
  }
  __syncthreads();

  // ---- MFMA phase: wave wv owns points [wv*64, wv*64+64) ----
  unsigned short* __restrict__ act = &ACTs[wv][0];
  #pragma unroll 1
  for (int tt = 0; tt < 4; ++tt) {
    const int tb = wv * 64 + tt * 16;                 // block-local point base
    const size_t gpt = (size_t)blockIdx.x * 256 + tb; // global point base
    // L1: 32 -> 64, relu
    const short8 a1 = *reinterpret_cast<const short8*>(&Xs[(tb + m) * 40 + ks * 8]);
    #pragma unroll
    for (int t = 0; t < 4; ++t) {
      f32x4 z = {0.f, 0.f, 0.f, 0.f};
      const f32x4 d = __builtin_amdgcn_mfma_f32_16x16x32_bf16(a1, w1f[t], z, 0, 0, 0);
      #pragma unroll
      for (int rr = 0; rr < 4; ++rr)
        act[(ks * 4 + rr) * 72 + t * 16 + m] = f2bf(fmaxf(d[rr], 0.0f));
    }
    // W2: 64 -> 16 (h), no activation
    {
      const short8 a2k0 = *reinterpret_cast<const short8*>(&act[m * 72 + ks * 8]);
      const short8 a2k1 = *reinterpret_cast<const short8*>(&act[m * 72 + 32 + ks * 8]);
      f32x4 dh = {0.f, 0.f, 0.f, 0.f};
      dh = __builtin_amdgcn_mfma_f32_16x16x32_bf16(a2k0, w2f[0], dh, 0, 0, 0);
      dh = __builtin_amdgcn_mfma_f32_16x16x32_bf16(a2k1, w2f[1], dh, 0, 0, 0);
      #pragma unroll
      for (int rr = 0; rr < 4; ++rr) {
        const size_t pt = gpt + ks * 4 + rr;
        if (m == 0 && pt < (size_t)N) out[3 * (size_t)N + pt] = expf(dh[rr]);
        CIs[(tb + ks * 4 + rr) * 40 + 16 + m] = f2bf(dh[rr]);  // ci[16..31] = h
      }
    }
    // Lc1: 32 -> 64, relu
    const short8 a3 = *reinterpret_cast<const short8*>(&CIs[(tb + m) * 40 + ks * 8]);
    #pragma unroll
    for (int t = 0; t < 4; ++t) {
      f32x4 z = {0.f, 0.f, 0.f, 0.f};
      const f32x4 d = __builtin_amdgcn_mfma_f32_16x16x32_bf16(a3, wc1f[t], z, 0, 0, 0);
      #pragma unroll
      for (int rr = 0; rr < 4; ++rr)
        act[(ks * 4 + rr) * 72 + t * 16 + m] = f2bf(fmaxf(d[rr], 0.0f));
    }
    // Lc2: 64 -> 64 (relu applied in epilogue)
    f32x4 e0, e1, e2, e3;
    {
      const short8 a4k0 = *reinterpret_cast<const short8*>(&act[m * 72 + ks * 8]);
      const short8 a4k1 = *reinterpret_cast<const short8*>(&act[m * 72 + 32 + ks * 8]);
      f32x4 z = {0.f, 0.f, 0.f, 0.f};
      e0 = __builtin_amdgcn_mfma_f32_16x16x32_bf16(a4k0, wc2f[0][0], z, 0, 0, 0);
      e0 = __builtin_amdgcn_mfma_f32_16x16x32_bf16(a4k1, wc2f[0][1], e0, 0, 0, 0);
      e1 = __builtin_amdgcn_mfma_f32_16x16x32_bf16(a4k0, wc2f[1][0], z, 0, 0, 0);
      e1 = __builtin_amdgcn_mfma_f32_16x16x32_bf16(a4k1, wc2f[1][1], e1, 0, 0, 0);
      e2 = __builtin_amdgcn_mfma_f32_16x16x32_bf16(a4k0, wc2f[2][0], z, 0, 0, 0);
      e2 = __builtin_amdgcn_mfma_f32_16x16x32_bf16(a4k1, wc2f[2][1], e2, 0, 0, 0);
      e3 = __builtin_amdgcn_mfma_f32_16x16x32_bf16(a4k0, wc2f[3][0], z, 0, 0, 0);
      e3 = __builtin_amdgcn_mfma_f32_16x16x32_bf16(a4k1, wc2f[3][1], e3, 0, 0, 0);
    }
    // Wc3 epilogue: logit[c][r] = sum_t relu(e_t[r]) * Wc3[c][t*16+m]
    float lg0[4], lg1[4], lg2[4];
    {
      const float w00 = W3s[0 * 64 + 0 * 16 + m], w01 = W3s[0 * 64 + 1 * 16 + m],
                  w02 = W3s[0 * 64 + 2 * 16 + m], w03 = W3s[0 * 64 + 3 * 16 + m];
      const float w10 = W3s[1 * 64 + 0 * 16 + m], w11 = W3s[1 * 64 + 1 * 16 + m],
                  w12 = W3s[1 * 64 + 2 * 16 + m], w13 = W3s[1 * 64 + 3 * 16 + m];
      const float w20 = W3s[2 * 64 + 0 * 16 + m], w21 = W3s[2 * 64 + 1 * 16 + m],
                  w22 = W3s[2 * 64 + 2 * 16 + m], w23 = W3s[2 * 64 + 3 * 16 + m];
      #pragma unroll
      for (int rr = 0; rr < 4; ++rr) {
        const float v0 = fmaxf(e0[rr], 0.0f), v1 = fmaxf(e1[rr], 0.0f);
        const float v2 = fmaxf(e2[rr], 0.0f), v3 = fmaxf(e3[rr], 0.0f);
        lg0[rr] = fmaf(v0, w00, fmaf(v1, w01, fmaf(v2, w02, v3 * w03)));
        lg1[rr] = fmaf(v0, w10, fmaf(v1, w11, fmaf(v2, w12, v3 * w13)));
        lg2[rr] = fmaf(v0, w20, fmaf(v1, w21, fmaf(v2, w22, v3 * w23)));
      }
    }
    // butterfly over the 16-lane neuron group
    #pragma unroll
    for (int st = 1; st < 16; st <<= 1) {
      #pragma unroll
      for (int rr = 0; rr < 4; ++rr) {
        lg0[rr] += __shfl_xor(lg0[rr], st, 64);
        lg1[rr] += __shfl_xor(lg1[rr], st, 64);
        lg2[rr] += __shfl_xor(lg2[rr], st, 64);
      }
    }
    #pragma unroll
    for (int rr = 0; rr < 4; ++rr) {
      const size_t pt = gpt + ks * 4 + rr;
      if (pt < (size_t)N) {
        if (m == 0) out[3 * pt + 0] = 1.0f / (1.0f + expf(-lg0[rr]));
        if (m == 1) out[3 * pt + 1] = 1.0f / (1.0f + expf(-lg1[rr]));
        if (m == 2) out[3 * pt + 2] = 1.0f / (1.0f + expf(-lg2[rr]));
      }
    }
  }
}

// ---------------------------------------------------------------------------
// Fallback: round-2 fused kernel (used only if ws_size is too small).
// ---------------------------------------------------------------------------
__global__ void __launch_bounds__(THREADS)
htrf_fused(const float* __restrict__ xyzs, const float* __restrict__ dirs,
           const float* __restrict__ grid, const float* __restrict__ W1,
           const float* __restrict__ W2, const float* __restrict__ Wc1,
           const float* __restrict__ Wc2, const float* __restrict__ Wc3,
           float* __restrict__ out, int N) {
  __shared__ float sbuf[THREADS * 33];
  const int tid = threadIdx.x;
  const int n = blockIdx.x * THREADS + tid;
  if (n >= N) return;
  float* __restrict__ my = sbuf + tid * 33;

  const float4 p = reinterpret_cast<const float4*>(xyzs)[n];
  const float q0 = (p.x + 1.0f) * 0.5f;
  const float q1 = (p.y + 1.0f) * 0.5f;
  const float q2 = (p.z + 1.0f) * 0.5f;
  const float q3 = p.w;

  #pragma unroll 1
  for (int l = 0; l < 16; ++l) {
    const float s = kScale[l];
    const float pos0 = fmaf(q0, s, 0.5f);
    const float pos1 = fmaf(q1, s, 0.5f);
    const float pos2 = fmaf(q2, s, 0.5f);
    const float pos3 = fmaf(q3, s, 0.5f);
    const float fl0 = floorf(pos0), fl1 = floorf(pos1);
    const float fl2 = floorf(pos2), fl3 = floorf(pos3);
    const float f0 = pos0 - fl0, f1 = pos1 - fl1;
    const float f2 = pos2 - fl2, f3 = pos3 - fl3;
    const int g0 = (int)fl0, g1 = (int)fl1, g2 = (int)fl2, g3 = (int)fl3;

    float wxy[4], wzt[4];
    {
      const float u0 = 1.0f - f0, u1 = 1.0f - f1, u2 = 1.0f - f2, u3 = 1.0f - f3;
      wxy[0] = u0 * u1; wxy[1] = f0 * u1; wxy[2] = u0 * f1; wxy[3] = f0 * f1;
      wzt[0] = u2 * u3; wzt[1] = f2 * u3; wzt[2] = u2 * f3; wzt[3] = f2 * f3;
    }

    unsigned idx[16];
    if (l < 4) {
      const int rr = kRes[l];
      const int r2 = rr * rr, r3 = r2 * rr;
      const int sxy[4] = {g0 + g1 * rr, g0 + 1 + g1 * rr,
                          g0 + (g1 + 1) * rr, g0 + 1 + (g1 + 1) * rr};
      const int szt[4] = {g2 * r2 + g3 * r3, (g2 + 1) * r2 + g3 * r3,
                          g2 * r2 + (g3 + 1) * r3, (g2 + 1) * r2 + (g3 + 1) * r3};
      #pragma unroll
      for (int cc = 0; cc < 16; ++cc) {
        const int v = sxy[cc & 3] + szt[cc >> 2];
        idx[cc] = (unsigned)(v < (int)TMASK ? v : (int)TMASK);
      }
    } else {
      const unsigned hx0 = (unsigned)g0,               hx1 = (unsigned)(g0 + 1);
      const unsigned hy0 = (unsigned)g1 * 2654435761u, hy1 = (unsigned)(g1 + 1) * 2654435761u;
      const unsigned hz0 = (unsigned)g2 * 805459861u,  hz1 = (unsigned)(g2 + 1) * 805459861u;
      const unsigned ht0 = (unsigned)g3 * 3674351687u, ht1 = (unsigned)(g3 + 1) * 3674351687u;
      const unsigned sxy[4] = {hx0 ^ hy0, hx1 ^ hy0, hx0 ^ hy1, hx1 ^ hy1};
      const unsigned szt[4] = {hz0 ^ ht0, hz1 ^ ht0, hz0 ^ ht1, hz1 ^ ht1};
      #pragma unroll
      for (int cc = 0; cc < 16; ++cc)
        idx[cc] = (sxy[cc & 3] ^ szt[cc >> 2]) & TMASK;
    }

    const float2* __restrict__ gl =
        reinterpret_cast<const float2*>(grid) + ((size_t)l << 19);
    float2 vv[16];
    #pragma unroll
    for (int cc = 0; cc < 16; ++cc) vv[cc] = gl[idx[cc]];
    float a0 = 0.0f, a1 = 0.0f;
    #pragma unroll
    for (int cc = 0; cc < 16; ++cc) {
      const float w = wxy[cc & 3] * wzt[cc >> 2];
      a0 = fmaf(w, vv[cc].x, a0);
      a1 = fmaf(w, vv[cc].y, a1);
    }
    my[2 * l] = a0;
    my[2 * l + 1] = a1;
  }

  float fr[32];
  #pragma unroll
  for (int k = 0; k < 32; ++k) fr[k] = my[k];

  float h[16];
  #pragma unroll
  for (int i = 0; i < 16; ++i) h[i] = 0.0f;

  #pragma unroll 1
  for (int j = 0; j < 64; ++j) {
    const float* __restrict__ w = W1 + j * 32;
    float b0 = 0.f, b1 = 0.f, b2 = 0.f, b3 = 0.f;
    #pragma unroll
    for (int k = 0; k < 32; k += 4) {
      b0 = fmaf(fr[k + 0], w[k + 0], b0);
      b1 = fmaf(fr[k + 1], w[k + 1], b1);
      b2 = fmaf(fr[k + 2], w[k + 2], b2);
      b3 = fmaf(fr[k + 3], w[k + 3], b3);
    }
    const float act = fmaxf((b0 + b1) + (b2 + b3), 0.0f);
    #pragma unroll
    for (int i = 0; i < 16; ++i) h[i] = fmaf(act, W2[i * 64 + j], h[i]);
  }
  const float sigma = expf(h[0]);

  const float dxr = dirs[3 * n + 0], dyr = dirs[3 * n + 1], dzr = dirs[3 * n + 2];
  const float x = fmaf(dxr, 2.0f, -1.0f);
  const float y = fmaf(dyr, 2.0f, -1.0f);
  const float z = fmaf(dzr, 2.0f, -1.0f);
  const float xy = x * y, xz = x * z, yz = y * z;
  const float x2 = x * x, y2 = y * y, z2 = z * z;
  float ci[32];
  ci[0]  = 0.28209479177387814f;
  ci[1]  = -0.48860251190291987f * y;
  ci[2]  = 0.48860251190291987f * z;
  ci[3]  = -0.48860251190291987f * x;
  ci[4]  = 1.0925484305920792f * xy;
  ci[5]  = -1.0925484305920792f * yz;
  ci[6]  = 0.94617469575756f * z2 - 0.31539156525252f;
  ci[7]  = -1.0925484305920792f * xz;
  ci[8]  = 0.5462742152960396f * x2 - 0.5462742152960396f * y2;
  ci[9]  = 0.5900435899266435f * y * (-3.0f * x2 + y2);
  ci[10] = 2.890611442640554f * xy * z;
  ci[11] = 0.4570457994644657f * y * (1.0f - 5.0f * z2);
  ci[12] = 0.3731763325901154f * z * (5.0f * z2 - 3.0f);
  ci[13] = 0.4570457994644657f * x * (1.0f - 5.0f * z2);
  ci[14] = 1.445305721320277f * z * (x2 - y2);
  ci[15] = 0.5900435899266435f * x * (-x2 + 3.0f * y2);
  #pragma unroll
  for (int i = 0; i < 16; ++i) ci[16 + i] = h[i];

  float c2p[64];
  #pragma unroll
  for (int i = 0; i < 64; ++i) c2p[i] = 0.0f;

  #pragma unroll 1
  for (int j = 0; j < 64; ++j) {
    const float* __restrict__ w = Wc1 + j * 32;
    float b0 = 0.f, b1 = 0.f, b2 = 0.f, b3 = 0.f;
    #pragma unroll
    for (int k = 0; k < 32; k += 4) {
      b0 = fmaf(ci[k + 0], w[k + 0], b0);
      b1 = fmaf(ci[k + 1], w[k + 1], b1);
      b2 = fmaf(ci[k + 2], w[k + 2], b2);
      b3 = fmaf(ci[k + 3], w[k + 3], b3);
    }
    const float act = fmaxf((b0 + b1) + (b2 + b3), 0.0f);
    #pragma unroll
    for (int i = 0; i < 64; ++i) c2p[i] = fmaf(act, Wc2[i * 64 + j], c2p[i]);
  }

  float l0a = 0.f, l0b = 0.f, l1a = 0.f, l1b = 0.f, l2a = 0.f, l2b = 0.f;
  #pragma unroll
  for (int i = 0; i < 64; i += 2) {
    const float a0r = fmaxf(c2p[i], 0.0f);
    const float a1r = fmaxf(c2p[i + 1], 0.0f);
    l0a = fmaf(a0r, Wc3[0 * 64 + i], l0a);
    l0b = fmaf(a1r, Wc3[0 * 64 + i + 1], l0b);
    l1a = fmaf(a0r, Wc3[1 * 64 + i], l1a);
    l1b = fmaf(a1r, Wc3[1 * 64 + i + 1], l1b);
    l2a = fmaf(a0r, Wc3[2 * 64 + i], l2a);
    l2b = fmaf(a1r, Wc3[2 * 64 + i + 1], l2b);
  }
  out[3 * n + 0] = 1.0f / (1.0f + expf(-(l0a + l0b)));
  out[3 * n + 1] = 1.0f / (1.0f + expf(-(l1a + l1b)));
  out[3 * n + 2] = 1.0f / (1.0f + expf(-(l2a + l2b)));
  out[3 * N + n] = sigma;
}

extern "C" void kernel_launch(void* const* d_in, const int* in_sizes, int n_in,
                              void* d_out, int out_size, void* d_ws, size_t ws_size,
                              hipStream_t stream) {
  const int N = in_sizes[0] / 4;
  const size_t need = (size_t)12 * (size_t)N * sizeof(float2);
  if (ws_size >= need) {
    const int CH = (N + THREADS - 1) / THREADS;   // point chunks per level
    const int H0 = (CH + 1) / 2;                  // phase-2 split point
    const int NB = 8 * (CH + H0);                 // phase1: 8*CH, phase2: 8*H0
    const int PB = (N + THREADS - 1) / THREADS;
    htrf_encode<<<dim3(NB), dim3(THREADS), 0, stream>>>(
        (const float*)d_in[0], (const float*)d_in[2], (float2*)d_ws, N, CH, H0);
    htrf_mlp_mfma<<<dim3(PB), dim3(THREADS), 0, stream>>>(
        (const float*)d_in[0], (const float*)d_in[1], (const float*)d_in[2],
        (const float*)d_in[3], (const float*)d_in[4], (const float*)d_in[5],
        (const float*)d_in[6], (const float*)d_in[7], (const float2*)d_ws,
        (float*)d_out, N);
  } else {
    htrf_fused<<<dim3((N + THREADS - 1) / THREADS), dim3(THREADS), 0, stream>>>(
        (const float*)d_in[0], (const float*)d_in[1], (const float*)d_in[2],
        (const float*)d_in[3], (const float*)d_in[4], (const float*)d_in[5],
        (const float*)d_in[6], (const float*)d_in[7], (float*)d_out, N);
  }
}